// Round 7
// baseline (47.309 us; speedup 1.0000x reference)
//
#include <hip/hip_runtime.h>

typedef float v2f __attribute__((ext_vector_type(2)));

// Structural constants (mirror reference)
#define NPOSE 64
#define NROT  128
#define NATOM 8
#define EPS   1e-2f

#define TS    16                 // rotamer tile size
#define NTILE (NROT / TS)        // 8 tiles per axis
#define NPAIR (NTILE * (NTILE + 1) / 2)   // 36 tile pairs (ti <= tj)
#define CSTR  28                 // coord LDS row stride: 24 + 4 pad -> 112B, 16B-aligned rows
#define SSTR  17                 // result tile row stride (16 + 1 pad)

__global__ __launch_bounds__(256, 6) void rot_score_kernel(
    const float* __restrict__ coords,
    float* __restrict__ out)
{
    __shared__ float ldsI[TS * CSTR];
    __shared__ float ldsJ[TS * CSTR];
    __shared__ float res0[TS * SSTR];
    __shared__ float res1[TS * SSTR];

    const int bid = blockIdx.x;
    const int p   = bid / NPAIR;
    int t = bid - p * NPAIR;
    int ti = 0;
    while (t >= NTILE - ti) { t -= NTILE - ti; ++ti; }   // unrank upper triangle
    const int tj = ti + t;

    const int tid = threadIdx.x;
    const float* src = coords + (size_t)p * (NROT * NATOM * 3);

    // Stage the two 16-rotamer coordinate sets (16 x 24 floats each), coalesced reads.
    for (int idx = tid; idx < 2 * TS * 24; idx += 256) {
        const int set = idx >= TS * 24;
        const int loc = idx - set * (TS * 24);
        const int r   = loc / 24;
        const int k   = loc - r * 24;
        const float v = src[(set ? tj : ti) * (TS * 24) + loc];
        (set ? ldsJ : ldsI)[r * CSTR + k] = v;
    }
    __syncthreads();

    const int ty = tid >> 4;    // i within tile (0..15)
    const int tx = tid & 15;    // j within tile (0..15)

    // i-rotamer fully in registers (broadcast reads, 6x ds_read_b128).
    float4 xi4[6];
    {
        const float4* rowI = (const float4*)&ldsI[ty * CSTR];
#pragma unroll
        for (int k = 0; k < 6; ++k) xi4[k] = rowI[k];
    }
    float* xi = (float*)xi4;

    // Per-atom squared norms; pre-scale xi by -2 so d2 = (sqi+sqj) + sum(xi2*xj).
    float sqi[NATOM];
#pragma unroll
    for (int a = 0; a < NATOM; ++a)
        sqi[a] = fmaf(xi[a*3+2], xi[a*3+2], fmaf(xi[a*3+1], xi[a*3+1], xi[a*3+0]*xi[a*3+0]));
#pragma unroll
    for (int k = 0; k < 24; ++k) xi[k] = xi[k] * -2.0f;

    const float SCH_S = -12102203.0f;   // -(2^23)/ln2  (Schraudolph exp)
    const float SCH_B = 1064866805.0f;  // bias
    const v2f veps = { EPS, EPS };
    const float* rowJ = &ldsJ[tx * CSTR];   // 16B-aligned row base

    // 2-way split accumulators (bp parity) to shorten dependent chains.
    v2f s0va = {0.f,0.f}, s0vb = {0.f,0.f}, s1va = {0.f,0.f}, s1vb = {0.f,0.f};

#pragma unroll
    for (int bp = 0; bp < 4; ++bp) {
        // Stream 6 j-floats for atoms (2bp, 2bp+1); static offsets -> merged ds_reads.
        const float j0 = rowJ[bp*6 + 0];
        const float j1 = rowJ[bp*6 + 1];
        const float j2 = rowJ[bp*6 + 2];
        const float j3 = rowJ[bp*6 + 3];
        const float j4 = rowJ[bp*6 + 4];
        const float j5 = rowJ[bp*6 + 5];
        const v2f ax = { j0, j3 };
        const v2f ay = { j1, j4 };
        const v2f az = { j2, j5 };
        const v2f sj = __builtin_elementwise_fma(az, az,
                        __builtin_elementwise_fma(ay, ay, ax * ax));
#pragma unroll
        for (int a = 0; a < NATOM; ++a) {
            v2f t = sj + sqi[a];                                    // pk_add (splat)
            t = __builtin_elementwise_fma((v2f)(xi[a*3+0]), ax, t);
            t = __builtin_elementwise_fma((v2f)(xi[a*3+1]), ay, t);
            t = __builtin_elementwise_fma((v2f)(xi[a*3+2]), az, t); // t = d2 pair
            t = __builtin_elementwise_max(t, veps);
            const v2f rs = { __builtin_amdgcn_rsqf(t.x),
                             __builtin_amdgcn_rsqf(t.y) };
            const v2f dv = t * rs;                                  // sqrt(d2)
            const v2f st = __builtin_elementwise_fma(dv, (v2f)(SCH_S), (v2f)(SCH_B));
            v2f e;
            e.x = __int_as_float((int)st.x);                        // ~ exp(-d)
            e.y = __int_as_float((int)st.y);
            if (bp & 1) {
                s0va = __builtin_elementwise_fma(rs, rs, s0va);     // += 1/d2
                s1va += e;
            } else {
                s0vb = __builtin_elementwise_fma(rs, rs, s0vb);
                s1vb += e;
            }
        }
    }
    const v2f s0v = s0va + s0vb;
    const v2f s1v = s1va + s1vb;
    const float s0 = s0v.x + s0v.y;
    const float s1 = s1v.x + s1v.y;

    // Stage results for the coalesced mirror write.
    res0[ty * SSTR + tx] = s0;
    res1[ty * SSTR + tx] = s1;

    const int nnz = NPOSE * NROT * NROT;
    const int gi  = ti * TS + ty;
    const int gj  = tj * TS + tx;
    const int n   = (p * NROT + gi) * NROT + gj;

    out[0 * nnz + n] = s0;
    out[1 * nnz + n] = s1;
    out[2 * nnz + n] = (float)p;
    out[3 * nnz + n] = (float)(p * NROT + gi);
    out[4 * nnz + n] = (float)(p * NROT + gj);

    if (ti != tj) {              // block-uniform branch
        __syncthreads();
        const float m0 = res0[tx * SSTR + ty];   // value of pair (ti*TS+tx, tj*TS+ty)
        const float m1 = res1[tx * SSTR + ty];
        const int mi = tj * TS + ty;
        const int mj = ti * TS + tx;
        const int nm = (p * NROT + mi) * NROT + mj;
        out[0 * nnz + nm] = m0;
        out[1 * nnz + nm] = m1;
        out[2 * nnz + nm] = (float)p;
        out[3 * nnz + nm] = (float)(p * NROT + mi);
        out[4 * nnz + nm] = (float)(p * NROT + mj);
    }
}

extern "C" void kernel_launch(void* const* d_in, const int* in_sizes, int n_in,
                              void* d_out, int out_size, void* d_ws, size_t ws_size,
                              hipStream_t stream) {
    (void)in_sizes; (void)n_in; (void)d_ws; (void)ws_size; (void)out_size;
    const float* coords = (const float*)d_in[0];
    float* out = (float*)d_out;

    dim3 grid(NPOSE * NPAIR);   // 64 poses x 36 upper-triangle tile pairs = 2304 blocks
    dim3 block(256);
    rot_score_kernel<<<grid, block, 0, stream>>>(coords, out);
}

// Round 8
// 26.436 us; speedup vs baseline: 1.7896x; 1.7896x over previous
//
#include <hip/hip_runtime.h>

typedef float v2f __attribute__((ext_vector_type(2)));

// Structural constants (mirror reference)
#define NPOSE 64
#define NROT  128
#define NATOM 8
#define EPS   1e-2f

#define TS    16                 // rotamer tile size
#define NTILE (NROT / TS)        // 8 tiles per axis
#define NPAIR (NTILE * (NTILE + 1) / 2)   // 36 tile pairs (ti <= tj)
#define CSTR  28                 // coord LDS row stride: 24 + 4 pad -> 112B, 16B-aligned rows
#define SSTR  17                 // result tile row stride (16 + 1 pad)

// Target: <=64 VGPR -> 8 waves/SIMD resident (32 waves/CU).
__global__ __launch_bounds__(256, 8) void rot_score_kernel(
    const float* __restrict__ coords,
    float* __restrict__ out)
{
    __shared__ float ldsI[TS * CSTR];
    __shared__ float ldsJ[TS * CSTR];
    __shared__ float res0[TS * SSTR];
    __shared__ float res1[TS * SSTR];

    const int bid = blockIdx.x;
    const int p   = bid / NPAIR;
    int t = bid - p * NPAIR;
    int ti = 0;
    while (t >= NTILE - ti) { t -= NTILE - ti; ++ti; }   // unrank upper triangle
    const int tj = ti + t;

    const int tid = threadIdx.x;
    const float* src = coords + (size_t)p * (NROT * NATOM * 3);

    // Stage the two 16-rotamer coordinate sets (16 x 24 floats each), coalesced reads.
    for (int idx = tid; idx < 2 * TS * 24; idx += 256) {
        const int set = idx >= TS * 24;
        const int loc = idx - set * (TS * 24);
        const int r   = loc / 24;
        const int k   = loc - r * 24;
        const float v = src[(set ? tj : ti) * (TS * 24) + loc];
        (set ? ldsJ : ldsI)[r * CSTR + k] = v;
    }
    __syncthreads();

    const int ty = tid >> 4;    // i within tile (0..15)
    const int tx = tid & 15;    // j within tile (0..15)

    const float* rowI = &ldsI[ty * CSTR];   // 16B-aligned row bases
    const float* rowJ = &ldsJ[tx * CSTR];

    const float SCH_S = -12102203.0f;   // -(2^23)/ln2  (Schraudolph exp)
    const float SCH_B = 1064866805.0f;  // bias
    const v2f veps = { EPS, EPS };

    v2f s0v = { 0.0f, 0.0f }, s1v = { 0.0f, 0.0f };

    // Two i-atom halves, NOT unrolled: keeps xi live set at 12 floats + 4 norms.
#pragma unroll 1
    for (int ha = 0; ha < 2; ++ha) {
        float4 xiH[3];
        {
            const float4* rI = (const float4*)(rowI + ha * 12);
#pragma unroll
            for (int k = 0; k < 3; ++k) xiH[k] = rI[k];
        }
        float* xi = (float*)xiH;   // atoms 4*ha .. 4*ha+3

        float sqi[4];
#pragma unroll
        for (int a = 0; a < 4; ++a)
            sqi[a] = fmaf(xi[a*3+2], xi[a*3+2], fmaf(xi[a*3+1], xi[a*3+1], xi[a*3+0]*xi[a*3+0]));
#pragma unroll
        for (int k = 0; k < 12; ++k) xi[k] = xi[k] * -2.0f;

#pragma unroll
        for (int bp = 0; bp < 4; ++bp) {
            // Stream 6 j-floats for atoms (2bp, 2bp+1); static offsets -> merged ds_reads.
            const float j0 = rowJ[bp*6 + 0];
            const float j1 = rowJ[bp*6 + 1];
            const float j2 = rowJ[bp*6 + 2];
            const float j3 = rowJ[bp*6 + 3];
            const float j4 = rowJ[bp*6 + 4];
            const float j5 = rowJ[bp*6 + 5];
            const v2f ax = { j0, j3 };
            const v2f ay = { j1, j4 };
            const v2f az = { j2, j5 };
            const v2f sj = __builtin_elementwise_fma(az, az,
                            __builtin_elementwise_fma(ay, ay, ax * ax));
#pragma unroll
            for (int a = 0; a < 4; ++a) {
                v2f t = sj + sqi[a];                                    // pk_add (splat)
                t = __builtin_elementwise_fma((v2f)(xi[a*3+0]), ax, t);
                t = __builtin_elementwise_fma((v2f)(xi[a*3+1]), ay, t);
                t = __builtin_elementwise_fma((v2f)(xi[a*3+2]), az, t); // t = d2 pair
                t = __builtin_elementwise_max(t, veps);
                const v2f rs = { __builtin_amdgcn_rsqf(t.x),
                                 __builtin_amdgcn_rsqf(t.y) };
                s0v = __builtin_elementwise_fma(rs, rs, s0v);           // += 1/d2
                const v2f dv = t * rs;                                  // sqrt(d2)
                const v2f st = __builtin_elementwise_fma(dv, (v2f)(SCH_S), (v2f)(SCH_B));
                v2f e;
                e.x = __int_as_float((int)st.x);                        // ~ exp(-d)
                e.y = __int_as_float((int)st.y);
                s1v += e;
            }
        }
    }
    const float s0 = s0v.x + s0v.y;
    const float s1 = s1v.x + s1v.y;

    // Stage results for the coalesced mirror write.
    res0[ty * SSTR + tx] = s0;
    res1[ty * SSTR + tx] = s1;

    const int nnz = NPOSE * NROT * NROT;
    const int gi  = ti * TS + ty;
    const int gj  = tj * TS + tx;
    const int n   = (p * NROT + gi) * NROT + gj;

    out[0 * nnz + n] = s0;
    out[1 * nnz + n] = s1;
    out[2 * nnz + n] = (float)p;
    out[3 * nnz + n] = (float)(p * NROT + gi);
    out[4 * nnz + n] = (float)(p * NROT + gj);

    if (ti != tj) {              // block-uniform branch
        __syncthreads();
        const float m0 = res0[tx * SSTR + ty];   // value of pair (ti*TS+tx, tj*TS+ty)
        const float m1 = res1[tx * SSTR + ty];
        const int mi = tj * TS + ty;
        const int mj = ti * TS + tx;
        const int nm = (p * NROT + mi) * NROT + mj;
        out[0 * nnz + nm] = m0;
        out[1 * nnz + nm] = m1;
        out[2 * nnz + nm] = (float)p;
        out[3 * nnz + nm] = (float)(p * NROT + mi);
        out[4 * nnz + nm] = (float)(p * NROT + mj);
    }
}

extern "C" void kernel_launch(void* const* d_in, const int* in_sizes, int n_in,
                              void* d_out, int out_size, void* d_ws, size_t ws_size,
                              hipStream_t stream) {
    (void)in_sizes; (void)n_in; (void)d_ws; (void)ws_size; (void)out_size;
    const float* coords = (const float*)d_in[0];
    float* out = (float*)d_out;

    dim3 grid(NPOSE * NPAIR);   // 64 poses x 36 upper-triangle tile pairs = 2304 blocks
    dim3 block(256);
    rot_score_kernel<<<grid, block, 0, stream>>>(coords, out);
}